// Round 7
// baseline (284.591 us; speedup 1.0000x reference)
//
#include <hip/hip_runtime.h>
#include <hip/hip_fp16.h>

#define N_NODES 100000
#define N_EDGES 1600000
#define HDIM 64
#define NPB 512                                  // nodes per bucket (pow2)
#define NPB_SHIFT 9
#define NBUCK 196                                // ceil(100000/512)
#define CAP 16384                                // per-bucket slot capacity
#define NCHUNK 256                               // place blocks (keeps bufD runs ~128B)
#define CHUNK (N_EDGES / NCHUNK)                 // 6250 edges/block
#define GBLK 3125                                // gather blocks (32 rows, N = 3125*32)
#define DROWS 64                                 // dense rows/block (512 thr, 8 lanes/row)
#define DBLK ((N_NODES + DROWS - 1) / DROWS)     // 1563

typedef float f4v __attribute__((ext_vector_type(4)));

// ---------------- K0: init cursors + zero out-degree counters ----------------
__global__ void init_kernel(int* __restrict__ gcurD, int* __restrict__ degS) {
    int idx = blockIdx.x * 512 + threadIdx.x;
    if (idx < N_NODES) degS[idx] = 0;
    if (blockIdx.x == 0 && threadIdx.x < NBUCK) gcurD[threadIdx.x] = threadIdx.x * CAP;
}

__device__ inline uint2 f4_to_h4(float x, float y, float z, float w) {
    __half2 lo = __floats2half2_rn(x, y);
    __half2 hi = __floats2half2_rn(z, w);
    uint2 r;
    r.x = *(unsigned*)&lo;
    r.y = *(unsigned*)&hi;
    return r;
}

// ---------------- K1: place edges into dst-bucket regions + global out-degree count ----------------
// bufS/gcurS eliminated: out-degrees counted directly via global atomics on degS
// (400 KB, L2-resident). bufD entry: src | (local_dst << 17).
__global__ void place_kernel(const int* __restrict__ src, const int* __restrict__ dst,
                             int* __restrict__ gcurD, int* __restrict__ degS,
                             unsigned int* __restrict__ bufD) {
    __shared__ int hD[NBUCK], curD[NBUCK];
    int t = threadIdx.x, blk = blockIdx.x;     // 512 threads
    for (int i = t; i < NBUCK; i += 512) hD[i] = 0;
    __syncthreads();
    int e0 = blk * CHUNK;
    // pass 1: dst histogram (LDS) + src degree count (global, L2)
    for (int i = t; i < CHUNK; i += 512) {
        atomicAdd(&hD[dst[e0 + i] >> NPB_SHIFT], 1);
        atomicAdd(&degS[src[e0 + i]], 1);
    }
    __syncthreads();
    // reserve runs
    for (int i = t; i < NBUCK; i += 512)
        curD[i] = hD[i] ? atomicAdd(&gcurD[i], hD[i]) : 0;
    __syncthreads();
    // pass 2: scatter (chunk re-read is L1/L2-hot)
    for (int i = t; i < CHUNK; i += 512) {
        int s = src[e0 + i], d = dst[e0 + i];
        int pd = atomicAdd(&curD[d >> NPB_SHIFT], 1);
        bufD[pd] = (unsigned)s | ((unsigned)(d & (NPB - 1)) << 17);
    }
}

// ---------------- K2: dst-bucket counting sort ∥ dense layer-1 ----------------
// blocks [0,196): dst buckets -> csr_src, offs, inv_in (wave-shfl scan: 4 barriers, was 18)
// blocks [196,196+1563): dense-1: hw = (h * rsqrt(degS)[:,None]) @ W  (shfl form, 64 rows)
// LDS sum = 4.1K (bucket) + 16K (Wlds) = 20.2K @512thr -> 4 blocks/CU = thread cap anyway.
__global__ void bucket_dense_kernel(const unsigned int* __restrict__ bufD,
                                    const int* __restrict__ gcurD,
                                    int* __restrict__ csr_src, int2* __restrict__ offs,
                                    float* __restrict__ inv_in,
                                    const int* __restrict__ degS,
                                    const float* __restrict__ h, const float* __restrict__ W,
                                    uint2* __restrict__ hw, int n) {
    int t = threadIdx.x;   // blockDim = 512
    int blk = blockIdx.x;
    if (blk < NBUCK) {
        __shared__ int cnt[NPB], cur[NPB];
        __shared__ int wsum[8];
        int b = blk;
        int ebase = b * CAP;
        int ecnt  = gcurD[b] - ebase;
        cnt[t] = 0;
        __syncthreads();
        for (int i = t; i < ecnt; i += NPB)
            atomicAdd(&cnt[(int)(bufD[ebase + i] >> 17)], 1);
        __syncthreads();
        int v = cnt[t];
        // wave-level inclusive scan (64 lanes, 6 shfl steps, no barriers)
        int lane = t & 63, w = t >> 6;
        int p = v;
#pragma unroll
        for (int d = 1; d < 64; d <<= 1) {
            int x = __shfl_up(p, d, 64);
            if (lane >= d) p += x;
        }
        if (lane == 63) wsum[w] = p;
        __syncthreads();
        int base = 0;
#pragma unroll
        for (int i = 0; i < 8; ++i) base += (i < w) ? wsum[i] : 0;
        int excl = base + p - v;
        cur[t] = excl;
        int node = b * NPB + t;
        if (node < N_NODES) {
            offs[node] = make_int2(ebase + excl, ebase + excl + v);
            inv_in[node] = rsqrtf((float)max(v, 1));
        }
        __syncthreads();
        for (int i = t; i < ecnt; i += NPB) {
            unsigned en = bufD[ebase + i];
            int pos = atomicAdd(&cur[(int)(en >> 17)], 1);
            csr_src[ebase + pos] = (int)(en & 0x1FFFFu);
        }
    } else {
        // ---- dense layer-1 (shfl form): lane gl owns cols [8gl,8gl+8) ----
        __shared__ float Wlds[HDIM * HDIM];     // 16 KB
        for (int i = t; i < HDIM * HDIM / 4; i += 512)
            ((f4v*)Wlds)[i] = ((const f4v*)W)[i];

        int r = t >> 3, gl = t & 7;             // 64 rows, 8 lanes/row
        int row = (blk - NBUCK) * DROWS + r;
        f4v a0 = {0.f, 0.f, 0.f, 0.f}, a1 = a0;
        if (row < n) {
            float so = rsqrtf((float)max(degS[row], 1));
            a0 = __builtin_nontemporal_load((const f4v*)h + (long long)row * 16 + gl * 2 + 0);
            a1 = __builtin_nontemporal_load((const f4v*)h + (long long)row * 16 + gl * 2 + 1);
            a0.x *= so; a0.y *= so; a0.z *= so; a0.w *= so;
            a1.x *= so; a1.y *= so; a1.z *= so; a1.w *= so;
        }
        __syncthreads();

        float acc0 = 0.f, acc1 = 0.f, acc2 = 0.f, acc3 = 0.f;
        float acc4 = 0.f, acc5 = 0.f, acc6 = 0.f, acc7 = 0.f;
        int gbase = (t & 63) & 56;              // 8-lane group base within wave

#pragma unroll
        for (int k = 0; k < HDIM; ++k) {
            float av = ((k >> 2) & 1) ? a1[k & 3] : a0[k & 3];   // static component
            float ak = __shfl(av, gbase + (k >> 3), 64);
            f4v w0 = ((const f4v*)Wlds)[k * 16 + gl * 2 + 0];
            f4v w1 = ((const f4v*)Wlds)[k * 16 + gl * 2 + 1];
            acc0 = fmaf(ak, w0.x, acc0); acc1 = fmaf(ak, w0.y, acc1);
            acc2 = fmaf(ak, w0.z, acc2); acc3 = fmaf(ak, w0.w, acc3);
            acc4 = fmaf(ak, w1.x, acc4); acc5 = fmaf(ak, w1.y, acc5);
            acc6 = fmaf(ak, w1.z, acc6); acc7 = fmaf(ak, w1.w, acc7);
        }

        if (row < n) {
            hw[(long long)row * 16 + gl * 2 + 0] = f4_to_h4(acc0, acc1, acc2, acc3);
            hw[(long long)row * 16 + gl * 2 + 1] = f4_to_h4(acc4, acc5, acc6, acc7);
        }
    }
}

// accumulate one fp16x8 row-slice into the 8 f32 accumulators
#define ACC8(u)                                              \
    {                                                        \
        float2 f0 = __half22float2(*(__half2*)&(u).x);       \
        float2 f1 = __half22float2(*(__half2*)&(u).y);       \
        float2 f2 = __half22float2(*(__half2*)&(u).z);       \
        float2 f3 = __half22float2(*(__half2*)&(u).w);       \
        acc0 += f0.x; acc1 += f0.y; acc2 += f1.x; acc3 += f1.y; \
        acc4 += f2.x; acc5 += f2.y; acc6 += f3.x; acc7 += f3.y; \
    }

// ---------------- K3: fused layer-1 gather + layer-2 dense (EXACT R4 inner loop) ----------------
__global__ void gather_dense_kernel(const uint4* __restrict__ hw_in, const float* __restrict__ inv_in,
                                    const int* __restrict__ degS,
                                    const int2* __restrict__ offs, const int* __restrict__ csr_src,
                                    const float* __restrict__ bias, const float* __restrict__ W,
                                    uint2* __restrict__ hw_out, int n) {
    __shared__ float Wlds[HDIM * HDIM];     // 16 KB
    int t = threadIdx.x;
    for (int i = t; i < HDIM * HDIM / 4; i += 256)
        ((f4v*)Wlds)[i] = ((const f4v*)W)[i];

    int wave = t >> 6, lane = t & 63;
    int g = lane >> 3, gl = lane & 7;          // group 0..7, lane-in-group 0..7
    int row = blockIdx.x * 32 + wave * 8 + g;  // N = 3125 * 32 exactly -> always valid

    float acc0 = 0.f, acc1 = 0.f, acc2 = 0.f, acc3 = 0.f;
    float acc4 = 0.f, acc5 = 0.f, acc6 = 0.f, acc7 = 0.f;

    int2 oe = offs[row];
    int start = oe.x, end = oe.y;
    int gbase = g << 3;

    int jb = start;
    int mm = end - jb; if (mm > 8) mm = 8;
    int sidx = (mm > 0 && gl < mm) ? __builtin_nontemporal_load(csr_src + jb + gl) : 0;

    while (jb < end) {
        int jb2 = jb + 8;
        int mm2 = end - jb2; if (mm2 > 8) mm2 = 8;
        int sidx2 = (jb2 < end && gl < mm2) ? __builtin_nontemporal_load(csr_src + jb2 + gl) : 0;

        if (mm == 8) {
#pragma unroll
            for (int j = 0; j < 8; ++j) {
                int s = __shfl(sidx, gbase + j, 64);
                uint4 u = hw_in[(long long)s * 8 + gl];
                ACC8(u)
            }
        } else {
            for (int j = 0; j < mm; ++j) {
                int s = __shfl(sidx, gbase + j, 64);
                uint4 u = hw_in[(long long)s * 8 + gl];
                ACC8(u)
            }
        }
        jb = jb2; mm = mm2; sidx = sidx2;
    }

    // finish layer 1 in registers: h1 = relu(acc*inv_in + bias), pre-scale by inv_out[row]
    float sc = inv_in[row];
    float so = rsqrtf((float)max(degS[row], 1));   // per-ROW out-degree scale
    float4 b0 = ((const float4*)bias)[gl * 2 + 0];
    float4 b1 = ((const float4*)bias)[gl * 2 + 1];
    f4v h0, h1;
    h0.x = fmaxf(fmaf(acc0, sc, b0.x), 0.f) * so;
    h0.y = fmaxf(fmaf(acc1, sc, b0.y), 0.f) * so;
    h0.z = fmaxf(fmaf(acc2, sc, b0.z), 0.f) * so;
    h0.w = fmaxf(fmaf(acc3, sc, b0.w), 0.f) * so;
    h1.x = fmaxf(fmaf(acc4, sc, b1.x), 0.f) * so;
    h1.y = fmaxf(fmaf(acc5, sc, b1.y), 0.f) * so;
    h1.z = fmaxf(fmaf(acc6, sc, b1.z), 0.f) * so;
    h1.w = fmaxf(fmaf(acc7, sc, b1.w), 0.f) * so;

    __syncthreads();   // Wlds ready (all lanes reach here: no early returns)

    // layer-2 dense: hw_out[row] = (so*h1row) @ W
    float d0 = 0.f, d1 = 0.f, d2 = 0.f, d3 = 0.f;
    float d4 = 0.f, d5 = 0.f, d6 = 0.f, d7 = 0.f;
#pragma unroll
    for (int k = 0; k < HDIM; ++k) {
        float av = ((k >> 2) & 1) ? h1[k & 3] : h0[k & 3];   // static component
        float ak = __shfl(av, gbase + (k >> 3), 64);
        f4v w0 = ((const f4v*)Wlds)[k * 16 + gl * 2 + 0];
        f4v w1 = ((const f4v*)Wlds)[k * 16 + gl * 2 + 1];
        d0 = fmaf(ak, w0.x, d0); d1 = fmaf(ak, w0.y, d1);
        d2 = fmaf(ak, w0.z, d2); d3 = fmaf(ak, w0.w, d3);
        d4 = fmaf(ak, w1.x, d4); d5 = fmaf(ak, w1.y, d5);
        d6 = fmaf(ak, w1.z, d6); d7 = fmaf(ak, w1.w, d7);
    }

    hw_out[(long long)row * 16 + gl * 2 + 0] = f4_to_h4(d0, d1, d2, d3);
    hw_out[(long long)row * 16 + gl * 2 + 1] = f4_to_h4(d4, d5, d6, d7);
}

// ---------------- K4: final gather (EXACT R4 form): out = relu(inv_in*sum + b) ----------------
__global__ void gather_kernel(const uint4* __restrict__ hw, const float* __restrict__ inv_in,
                              const int2* __restrict__ offs, const int* __restrict__ csr_src,
                              const float* __restrict__ bias, float* __restrict__ out, int n) {
    int t = threadIdx.x;
    int wave = t >> 6, lane = t & 63;
    int g = lane >> 3, gl = lane & 7;
    int row = blockIdx.x * 32 + wave * 8 + g;
    if (row >= n) return;

    float acc0 = 0.f, acc1 = 0.f, acc2 = 0.f, acc3 = 0.f;
    float acc4 = 0.f, acc5 = 0.f, acc6 = 0.f, acc7 = 0.f;

    int2 oe = offs[row];
    int jb = oe.x, end = oe.y;
    int gbase = g << 3;

    int mm = end - jb; if (mm > 8) mm = 8;
    int sidx = (mm > 0 && gl < mm) ? __builtin_nontemporal_load(csr_src + jb + gl) : 0;

    while (jb < end) {
        int jb2 = jb + 8;
        int mm2 = end - jb2; if (mm2 > 8) mm2 = 8;
        int sidx2 = (jb2 < end && gl < mm2) ? __builtin_nontemporal_load(csr_src + jb2 + gl) : 0;

        if (mm == 8) {
#pragma unroll
            for (int j = 0; j < 8; ++j) {
                int s = __shfl(sidx, gbase + j, 64);
                uint4 u = hw[(long long)s * 8 + gl];
                ACC8(u)
            }
        } else {
            for (int j = 0; j < mm; ++j) {
                int s = __shfl(sidx, gbase + j, 64);
                uint4 u = hw[(long long)s * 8 + gl];
                ACC8(u)
            }
        }
        jb = jb2; mm = mm2; sidx = sidx2;
    }

    float sc = inv_in[row];
    float4 b0 = ((const float4*)bias)[gl * 2 + 0];
    float4 b1 = ((const float4*)bias)[gl * 2 + 1];
    f4v r0, r1;
    r0.x = fmaxf(fmaf(acc0, sc, b0.x), 0.f);
    r0.y = fmaxf(fmaf(acc1, sc, b0.y), 0.f);
    r0.z = fmaxf(fmaf(acc2, sc, b0.z), 0.f);
    r0.w = fmaxf(fmaf(acc3, sc, b0.w), 0.f);
    r1.x = fmaxf(fmaf(acc4, sc, b1.x), 0.f);
    r1.y = fmaxf(fmaf(acc5, sc, b1.y), 0.f);
    r1.z = fmaxf(fmaf(acc6, sc, b1.z), 0.f);
    r1.w = fmaxf(fmaf(acc7, sc, b1.w), 0.f);
    __builtin_nontemporal_store(r0, (f4v*)out + (long long)row * 16 + gl * 2 + 0);
    __builtin_nontemporal_store(r1, (f4v*)out + (long long)row * 16 + gl * 2 + 1);
}

extern "C" void kernel_launch(void* const* d_in, const int* in_sizes, int n_in,
                              void* d_out, int out_size, void* d_ws, size_t ws_size,
                              hipStream_t stream) {
    const float* features = (const float*)d_in[0];   // [N, 64]
    const float* W        = (const float*)d_in[1];   // [64, 64]
    const float* b        = (const float*)d_in[2];   // [64]
    const int*   src      = (const int*)d_in[3];     // [E]
    const int*   dst      = (const int*)d_in[4];     // [E]

    float* out = (float*)d_out;                      // [N, 64]

    // workspace layout (4-byte words)
    float* ws = (float*)d_ws;
    uint2* hw  = (uint2*)ws;                                            // N*32 words, row-major
    uint2* hw2 = (uint2*)(ws + (size_t)N_NODES * 32);                   // N*32 words, row-major
    unsigned int* bufD = (unsigned int*)(ws + (size_t)N_NODES * 64);    // NBUCK*CAP words
    int*   csr_src = (int*)(bufD + (size_t)NBUCK * CAP);                // NBUCK*CAP words
    int2*  offs    = (int2*)(csr_src + (size_t)NBUCK * CAP);            // N int2
    float* inv_in  = (float*)(offs + N_NODES);       // N
    int*   degS    = (int*)(inv_in + N_NODES);       // N (out-degree counters)
    int*   gcurD   = degS + N_NODES;                 // NBUCK

    const int N = N_NODES;

    // K0: zero degS + cursors (196 x 512 covers 100352 >= N)
    init_kernel<<<196, 512, 0, stream>>>(gcurD, degS);

    // K1: edge placement (dst buckets) + out-degree atomics; bufS eliminated
    place_kernel<<<NCHUNK, 512, 0, stream>>>(src, dst, gcurD, degS, bufD);

    // K2: dst-bucket counting sort (196 blocks) ∥ dense layer-1 (1563 blocks)
    bucket_dense_kernel<<<NBUCK + DBLK, 512, 0, stream>>>(
        bufD, gcurD, csr_src, offs, inv_in, degS, features, W, hw, N);

    // K3: fused layer-1 gather + layer-2 dense -> hw2
    gather_dense_kernel<<<GBLK, 256, 0, stream>>>(
        (const uint4*)hw, inv_in, degS, offs, csr_src, b, W, hw2, N);

    // K4: final gather -> out
    gather_kernel<<<GBLK, 256, 0, stream>>>(
        (const uint4*)hw2, inv_in, offs, csr_src, b, out, N);
}